// Round 21
// baseline (586.263 us; speedup 1.0000x reference)
//
#include <hip/hip_runtime.h>
#include <hip/hip_bf16.h>

#define D_MODEL   640
#define D_INNER   1280
#define D_STATE   34
#define D_CONV    4
#define DT_RANK   40
#define BATCH     2
#define SEQ       2048
#define XDBL_W    (DT_RANK + 2 * D_STATE)   // 108
#define M_TOTAL   (BATCH * SEQ)             // 4096
#define NCHUNK    4
#define CHLEN     (SEQ / NCHUNK)            // 512
#define RECW      68                        // record: 34 h_end + 34 P
#define PF        8

typedef __attribute__((ext_vector_type(8))) short short8v;   // bf16x8 (4 VGPR)
typedef __attribute__((ext_vector_type(4))) short short4v;   // bf16x4
typedef __attribute__((ext_vector_type(4))) float f32x4;     // MFMA acc

// Split f32 into bf16 hi (truncation) + bf16 lo (RNE of residual).
__device__ __forceinline__ void split_bf16(float x, short& hi, short& lo) {
    unsigned u  = __builtin_bit_cast(unsigned, x);
    unsigned uh = u & 0xFFFF0000u;
    hi = (short)(uh >> 16);
    float r = x - __builtin_bit_cast(float, uh);   // exact
    unsigned v = __builtin_bit_cast(unsigned, r);
    v += 0x7FFFu + ((v >> 16) & 1u);               // RNE to bf16
    lo = (short)(v >> 16);
}

__device__ __forceinline__ void split4(const float4& v, short4v& h, short4v& l) {
    float xs[4] = {v.x, v.y, v.z, v.w};
    #pragma unroll
    for (int j = 0; j < 4; ++j) { short hh, ll; split_bf16(xs[j], hh, ll); h[j] = hh; l[j] = ll; }
}

// ---------------------------------------------------------------------------
// Split-bf16 MFMA GEMM: C[M,N] = A[M,K] . B[N,K]^T  (fp32 in/out, ~fp32 acc).
// MODE: 0 = none, 2 = silu(v) for output rows >= D_INNER (merged in-proj)
// ---------------------------------------------------------------------------
template<int MODE>
__global__ __launch_bounds__(256) void gemm_mfma(
    const float* __restrict__ A, const float* __restrict__ B,
    float* __restrict__ C, int M, int N, int K, int lda, int ldb, int ldc)
{
    constexpr int BMt = 128, BKt = 32;
    constexpr int LDT = 40;                        // LDS row stride in shorts
    __shared__ short Ahi[BMt * LDT], Alo[BMt * LDT];
    __shared__ short Bhi[BMt * LDT], Blo[BMt * LDT];

    const int tid  = threadIdx.x;
    const long m0  = (long)blockIdx.y * BMt;
    const long n0  = (long)blockIdx.x * BMt;
    const int wid  = tid >> 6, lane = tid & 63;
    const int wr   = (wid >> 1) * 64;
    const int wc   = (wid & 1) * 64;
    const int lrow = lane & 15;
    const int lkb  = lane >> 4;

    const bool do_silu = (MODE == 2) && (m0 >= D_INNER);   // block-uniform

    f32x4 acc[4][4] = {};

    for (int k0 = 0; k0 < K; k0 += BKt) {
        __syncthreads();
        #pragma unroll
        for (int q = 0; q < 4; ++q) {
            int flat = tid + q * 256;
            int r  = flat >> 3;
            int f4 = (flat & 7) << 2;
            float4 va = *reinterpret_cast<const float4*>(&A[(m0 + r) * lda + k0 + f4]);
            float4 vb = *reinterpret_cast<const float4*>(&B[(n0 + r) * ldb + k0 + f4]);
            short4v ah, al, bh, bl;
            split4(va, ah, al);
            split4(vb, bh, bl);
            *reinterpret_cast<short4v*>(&Ahi[r * LDT + f4]) = ah;
            *reinterpret_cast<short4v*>(&Alo[r * LDT + f4]) = al;
            *reinterpret_cast<short4v*>(&Bhi[r * LDT + f4]) = bh;
            *reinterpret_cast<short4v*>(&Blo[r * LDT + f4]) = bl;
        }
        __syncthreads();

        short8v a_hi[4], a_lo[4], b_hi[4], b_lo[4];
        #pragma unroll
        for (int i = 0; i < 4; ++i) {
            int ar = (wr + i * 16 + lrow) * LDT + lkb * 8;
            int br = (wc + i * 16 + lrow) * LDT + lkb * 8;
            a_hi[i] = *reinterpret_cast<const short8v*>(&Ahi[ar]);
            a_lo[i] = *reinterpret_cast<const short8v*>(&Alo[ar]);
            b_hi[i] = *reinterpret_cast<const short8v*>(&Bhi[br]);
            b_lo[i] = *reinterpret_cast<const short8v*>(&Blo[br]);
        }
        #pragma unroll
        for (int i = 0; i < 4; ++i)
            #pragma unroll
            for (int j = 0; j < 4; ++j) {
                acc[i][j] = __builtin_amdgcn_mfma_f32_16x16x32_bf16(a_hi[i], b_hi[j], acc[i][j], 0, 0, 0);
                acc[i][j] = __builtin_amdgcn_mfma_f32_16x16x32_bf16(a_hi[i], b_lo[j], acc[i][j], 0, 0, 0);
                acc[i][j] = __builtin_amdgcn_mfma_f32_16x16x32_bf16(a_lo[i], b_hi[j], acc[i][j], 0, 0, 0);
            }
    }

    #pragma unroll
    for (int i = 0; i < 4; ++i) {
        long grow0 = m0 + wr + i * 16 + lkb * 4;
        #pragma unroll
        for (int j = 0; j < 4; ++j) {
            long gcol = n0 + wc + j * 16 + lrow;
            #pragma unroll
            for (int r = 0; r < 4; ++r) {
                float v = acc[i][j][r];
                if (do_silu) v = v * (1.0f / (1.0f + __expf(-v)));
                C[(grow0 + r) * ldc + gcol] = v;
            }
        }
    }
}

// ---------------------------------------------------------------------------
// Small f32 GEMM. A [M,K] (LAYA=0) or [K,M] (LAYA=1); B [N,K] row-major.
// MODE: 0 = none, 2 = softplus(v + bias[gm]).
// ---------------------------------------------------------------------------
#define BM 64
#define BN 64
#define BK 16

template<int LAYA, int MODE>
__global__ __launch_bounds__(256) void gemm_tn(
    const float* __restrict__ A, const float* __restrict__ B,
    float* __restrict__ C, int M, int N, int K, int lda, int ldb, int ldc,
    const float* __restrict__ bias)
{
    __shared__ float As[BK][BM + 4];
    __shared__ float Bs[BK][BN + 4];

    const int tid = threadIdx.x;
    const int m0 = blockIdx.y * BM;
    const int n0 = blockIdx.x * BN;
    const int tx = tid & 15;
    const int ty = tid >> 4;

    float acc[4][4] = {};

    for (int k0 = 0; k0 < K; k0 += BK) {
        #pragma unroll
        for (int i = 0; i < 4; ++i) {
            int idx = tid + i * 256;
            if (LAYA == 0) {
                int r = idx >> 4;
                int c = idx & 15;
                As[c][r] = (m0 + r < M && k0 + c < K)
                         ? A[(long)(m0 + r) * lda + (k0 + c)] : 0.0f;
            } else {
                int c = idx >> 6;
                int r = idx & 63;
                As[c][r] = (m0 + r < M && k0 + c < K)
                         ? A[(long)(k0 + c) * lda + (m0 + r)] : 0.0f;
            }
            int rb = idx >> 4;
            int cb = idx & 15;
            Bs[cb][rb] = (n0 + rb < N && k0 + cb < K)
                       ? B[(long)(n0 + rb) * ldb + (k0 + cb)] : 0.0f;
        }
        __syncthreads();

        #pragma unroll
        for (int k = 0; k < BK; ++k) {
            const float4 a4 = *reinterpret_cast<const float4*>(&As[k][ty * 4]);
            const float4 b4 = *reinterpret_cast<const float4*>(&Bs[k][tx * 4]);
            const float a_[4] = {a4.x, a4.y, a4.z, a4.w};
            const float b_[4] = {b4.x, b4.y, b4.z, b4.w};
            #pragma unroll
            for (int i = 0; i < 4; ++i)
                #pragma unroll
                for (int j = 0; j < 4; ++j)
                    acc[i][j] = fmaf(a_[i], b_[j], acc[i][j]);
        }
        __syncthreads();
    }

    #pragma unroll
    for (int i = 0; i < 4; ++i) {
        int gm = m0 + ty * 4 + i;
        if (gm >= M) continue;
        float bi = (MODE == 2) ? bias[gm] : 0.0f;
        #pragma unroll
        for (int j = 0; j < 4; ++j) {
            int gn = n0 + tx * 4 + j;
            if (gn >= N) continue;
            float v = acc[i][j];
            if (MODE == 2) {
                v += bi;
                v = (v > 15.0f) ? v : log1pf(__expf(v));   // softplus
            }
            C[(long)gm * ldc + gn] = v;
        }
    }
}

// ---------------------------------------------------------------------------
// Split-K f32 GEMM for x_dbl (non-transposed output [4096][108]):
// Cp[z] = A(K-major u_T slice) . B^T. Grid (N/64, M/64, 4).
// ---------------------------------------------------------------------------
__global__ __launch_bounds__(256) void gemm_splitk(
    const float* __restrict__ A, const float* __restrict__ B,
    float* __restrict__ Cp, int M, int N, int K, int lda, int ldb, int ldc)
{
    __shared__ float As[BK][BM + 4];
    __shared__ float Bs[BK][BN + 4];

    const int tid = threadIdx.x;
    const int m0 = blockIdx.y * BM;
    const int n0 = blockIdx.x * BN;
    const int z  = blockIdx.z;
    const int kseg = K / 4;
    const int kbeg = z * kseg;
    const int tx = tid & 15;
    const int ty = tid >> 4;

    float acc[4][4] = {};

    for (int k0 = kbeg; k0 < kbeg + kseg; k0 += BK) {
        #pragma unroll
        for (int i = 0; i < 4; ++i) {
            int idx = tid + i * 256;
            int c = idx >> 6;
            int r = idx & 63;
            As[c][r] = A[(long)(k0 + c) * lda + (m0 + r)];
            int rb = idx >> 4;
            int cb = idx & 15;
            Bs[cb][rb] = (n0 + rb < N) ? B[(long)(n0 + rb) * ldb + (k0 + cb)] : 0.0f;
        }
        __syncthreads();

        #pragma unroll
        for (int k = 0; k < BK; ++k) {
            const float4 a4 = *reinterpret_cast<const float4*>(&As[k][ty * 4]);
            const float4 b4 = *reinterpret_cast<const float4*>(&Bs[k][tx * 4]);
            const float a_[4] = {a4.x, a4.y, a4.z, a4.w};
            const float b_[4] = {b4.x, b4.y, b4.z, b4.w};
            #pragma unroll
            for (int i = 0; i < 4; ++i)
                #pragma unroll
                for (int j = 0; j < 4; ++j)
                    acc[i][j] = fmaf(a_[i], b_[j], acc[i][j]);
        }
        __syncthreads();
    }

    float* Cz = Cp + (long)z * M * ldc;
    #pragma unroll
    for (int i = 0; i < 4; ++i) {
        int gm = m0 + ty * 4 + i;
        #pragma unroll
        for (int j = 0; j < 4; ++j) {
            int gn = n0 + tx * 4 + j;
            if (gn < N) Cz[(long)gm * ldc + gn] = acc[i][j];
        }
    }
}

// Reduce 4 split-K partials: out[i] = sum_z part[z][i].  n = 4096*108 floats.
__global__ __launch_bounds__(256) void reduce4_kernel(
    const float* __restrict__ part, float* __restrict__ out, int n)
{
    int i4 = (blockIdx.x * 256 + threadIdx.x) * 4;
    if (i4 >= n) return;
    float4 s0 = *reinterpret_cast<const float4*>(&part[i4]);
    float4 s1 = *reinterpret_cast<const float4*>(&part[(long)n + i4]);
    float4 s2 = *reinterpret_cast<const float4*>(&part[(long)2 * n + i4]);
    float4 s3 = *reinterpret_cast<const float4*>(&part[(long)3 * n + i4]);
    float4 r;
    r.x = (s0.x + s1.x) + (s2.x + s3.x);
    r.y = (s0.y + s1.y) + (s2.y + s3.y);
    r.z = (s0.z + s1.z) + (s2.z + s3.z);
    r.w = (s0.w + s1.w) + (s2.w + s3.w);
    *reinterpret_cast<float4*>(&out[i4]) = r;
}

// ---------------------------------------------------------------------------
// Depthwise causal conv (width 4) + bias + SiLU on TRANSPOSED x [1280][4096].
// ---------------------------------------------------------------------------
__global__ __launch_bounds__(256) void conv_silu_kernel(
    const float* __restrict__ xT, const float* __restrict__ cw,
    const float* __restrict__ cb, float* __restrict__ uT)
{
    int idx = blockIdx.x * 256 + threadIdx.x;      // d*4096 + bs
    if (idx >= D_INNER * M_TOTAL) return;
    int bs = idx & (M_TOTAL - 1);
    int d  = idx >> 12;
    int s  = bs & (SEQ - 1);

    const float* xr = xT + idx;
    float acc = cb[d];
    #pragma unroll
    for (int k = 0; k < D_CONV; ++k) {
        int off = k - (D_CONV - 1);                // -3..0
        if (s + off >= 0)
            acc = fmaf(xr[off], cw[d * D_CONV + k], acc);
    }
    uT[idx] = acc * (1.0f / (1.0f + __expf(-acc)));
}

// ---------------------------------------------------------------------------
// LDS-tiled transpose: in [1280][4096] -> out [4096][1280]. 32x32 tiles.
// ---------------------------------------------------------------------------
__global__ __launch_bounds__(256) void transpose_kernel(
    const float* __restrict__ in, float* __restrict__ out)
{
    __shared__ float tile[32][33];
    const int tx = threadIdx.x & 31;
    const int ty = threadIdx.x >> 5;
    const int t0 = blockIdx.x * 32;
    const int d0 = blockIdx.y * 32;

    #pragma unroll
    for (int i = 0; i < 32; i += 8)
        tile[ty + i][tx] = in[(long)(d0 + ty + i) * M_TOTAL + t0 + tx];
    __syncthreads();
    #pragma unroll
    for (int i = 0; i < 32; i += 8)
        out[(long)(t0 + ty + i) * D_INNER + d0 + tx] = tile[tx][ty + i];
}

#define DPP_ADD(X_, CTRL_) {                                                 \
        int t_ = __builtin_amdgcn_update_dpp(                                \
            0, __builtin_bit_cast(int, X_), (CTRL_), 0xf, 0xf, true);        \
        X_ += __builtin_bit_cast(float, t_);                                 \
    }

// ---------------------------------------------------------------------------
// Chunked scan pass 1 (v8): r20 body, but 3 waves per block (one per chunk)
// with c forced into an SGPR via readfirstlane so sp/u stream bases stay on
// the scalar pipe (r18's failure mode avoided). Grid: one block per (b,d).
// ---------------------------------------------------------------------------
__global__ __launch_bounds__(192) void scan_part1(
    const float* __restrict__ xdbl,    // B at [bs*108 + 40 + n]
    const float* __restrict__ spT,     // softplus(dt+bias)[1280][4096]
    const float* __restrict__ A_log,
    const float* __restrict__ uT,      // u [1280][4096]
    float* __restrict__ rec)
{
    const int bd   = blockIdx.x;
    const int c    = __builtin_amdgcn_readfirstlane(threadIdx.x >> 6); // SGPR
    const int lane = threadIdx.x & 63;
    const int b = bd / D_INNER;
    const int d = bd % D_INNER;
    const bool act = lane < D_STATE;

    const float A_n = act ? -__expf(A_log[d * D_STATE + lane]) : 0.0f;

    const long base = (long)d * M_TOTAL + (long)b * SEQ + (long)c * CHLEN;
    const float* sp_p = spT + base;
    const float* u_p  = uT  + base;
    const float* bc_p = xdbl + ((long)b * SEQ + (long)c * CHLEN) * XDBL_W;

    float h = 0.0f, P = 1.0f;

    float aSP[PF], aU[PF], aB[PF];
    float bSP[PF], bU[PF], bB[PF];

#define LOADS1(SP_, U_, B_, T_) {                                            \
        int tt = (T_); tt = (tt < CHLEN) ? tt : (CHLEN - 1);                 \
        SP_ = sp_p[tt];                                                      \
        U_  = u_p [tt];                                                      \
        B_  = act ? bc_p[(long)tt * XDBL_W + DT_RANK + lane] : 0.0f;         \
    }

#define STEP1(SP_, U_, B_) {                                                 \
        float dA = __expf(SP_ * A_n);                                        \
        h = fmaf(dA, h, (SP_ * U_) * B_);                                    \
        P *= dA;                                                             \
    }

    #pragma unroll
    for (int i = 0; i < PF; ++i) LOADS1(aSP[i], aU[i], aB[i], i);

    for (int t0 = 0; t0 < CHLEN; t0 += 2 * PF) {
        #pragma unroll
        for (int i = 0; i < PF; ++i) LOADS1(bSP[i], bU[i], bB[i], t0 + PF + i);
        #pragma unroll
        for (int i = 0; i < PF; ++i) STEP1(aSP[i], aU[i], aB[i]);
        #pragma unroll
        for (int i = 0; i < PF; ++i) LOADS1(aSP[i], aU[i], aB[i], t0 + 2 * PF + i);
        #pragma unroll
        for (int i = 0; i < PF; ++i) STEP1(bSP[i], bU[i], bB[i]);
    }
#undef LOADS1
#undef STEP1

    if (act) {
        long cid = (long)bd * (NCHUNK - 1) + c;
        rec[cid * RECW + lane]      = h;
        rec[cid * RECW + 34 + lane] = P;
    }
}

// ---------------------------------------------------------------------------
// Chunked scan pass 3 (v8): r20 body, 4 waves per block (one per chunk),
// c in SGPR via readfirstlane -> uniform streams stay scalar. One block/(b,d).
// ---------------------------------------------------------------------------
__global__ __launch_bounds__(256) void scan_part3(
    const float* __restrict__ gT,      // silu(z)          [1280][4096]
    const float* __restrict__ xdbl,    // B/C at [bs*108 + 40(+34) + n]
    const float* __restrict__ spT,     // softplus(dt+bias)[1280][4096]
    const float* __restrict__ A_log,
    const float* __restrict__ D_skip,
    const float* __restrict__ rec,
    float* __restrict__ uT)            // in: u, out: y*g (in-place)
{
    const int bd   = blockIdx.x;
    const int c    = __builtin_amdgcn_readfirstlane(threadIdx.x >> 6); // SGPR
    const int lane = threadIdx.x & 63;
    const int b = bd / D_INNER;
    const int d = bd % D_INNER;
    const bool act = lane < D_STATE;

    const float A_n = act ? -__expf(A_log[d * D_STATE + lane]) : 0.0f;
    const float Dd  = D_skip[d];

    const long base = (long)d * M_TOTAL + (long)b * SEQ + (long)c * CHLEN;
    const float* sp_p = spT + base;
    const float* g_p  = gT  + base;
    float*       u_p  = uT  + base;
    const float* bc_p = xdbl + ((long)b * SEQ + (long)c * CHLEN) * XDBL_W;

    // ---- combine prologue: h_start from preceding chunks' records
    float h = 0.0f;
    for (int cc = 0; cc < c; ++cc) {
        long rbase = ((long)bd * (NCHUNK - 1) + cc) * RECW;
        float he = act ? rec[rbase + lane]      : 0.0f;
        float Pp = act ? rec[rbase + 34 + lane] : 0.0f;
        h = fmaf(Pp, h, he);
    }

    float aSP[PF], aU[PF], aG[PF], aB[PF], aC[PF];
    float bSP[PF], bU[PF], bG[PF], bB[PF], bC[PF];

#define LOADS(SP_, U_, G_, B_, C_, T_) {                                     \
        int tt = (T_); tt = (tt < CHLEN) ? tt : (CHLEN - 1);                 \
        SP_ = sp_p[tt];                                                      \
        U_  = u_p [tt];                                                      \
        G_  = g_p [tt];                                                      \
        const float* bcq = bc_p + (long)tt * XDBL_W + DT_RANK + lane;        \
        B_ = act ? bcq[0]       : 0.0f;                                      \
        C_ = act ? bcq[D_STATE] : 0.0f;                                      \
    }

#define STEP(SP_, U_, G_, B_, C_, T_) {                                      \
        float dA = __expf(SP_ * A_n);                                        \
        h = fmaf(dA, h, (SP_ * U_) * B_);                                    \
        float pp = h * C_;                                                   \
        DPP_ADD(pp, 0x111);   /* row_shr:1  */                               \
        DPP_ADD(pp, 0x112);   /* row_shr:2  */                               \
        DPP_ADD(pp, 0x114);   /* row_shr:4  */                               \
        DPP_ADD(pp, 0x118);   /* row_shr:8  */                               \
        DPP_ADD(pp, 0x142);   /* row_bcast:15 */                             \
        DPP_ADD(pp, 0x143);   /* row_bcast:31 */                             \
        if (lane == 63) {                                                    \
            float y = fmaf(U_, Dd, pp);                                      \
            u_p[T_] = y * G_;                                                \
        }                                                                    \
    }

    #pragma unroll
    for (int i = 0; i < PF; ++i) LOADS(aSP[i], aU[i], aG[i], aB[i], aC[i], i);

    for (int t0 = 0; t0 < CHLEN; t0 += 2 * PF) {
        #pragma unroll
        for (int i = 0; i < PF; ++i)
            LOADS(bSP[i], bU[i], bG[i], bB[i], bC[i], t0 + PF + i);
        #pragma unroll
        for (int i = 0; i < PF; ++i)
            STEP(aSP[i], aU[i], aG[i], aB[i], aC[i], t0 + i);
        #pragma unroll
        for (int i = 0; i < PF; ++i)
            LOADS(aSP[i], aU[i], aG[i], aB[i], aC[i], t0 + 2 * PF + i);
        #pragma unroll
        for (int i = 0; i < PF; ++i)
            STEP(bSP[i], bU[i], bG[i], bB[i], bC[i], t0 + PF + i);
    }
#undef LOADS
#undef STEP
}

// ---------------------------------------------------------------------------
extern "C" void kernel_launch(void* const* d_in, const int* in_sizes, int n_in,
                              void* d_out, int out_size, void* d_ws, size_t ws_size,
                              hipStream_t stream)
{
    const float* hs      = (const float*)d_in[0];
    const float* W_in    = (const float*)d_in[1];
    const float* conv_w  = (const float*)d_in[2];
    const float* conv_b  = (const float*)d_in[3];
    const float* W_x     = (const float*)d_in[4];
    const float* W_dt    = (const float*)d_in[5];
    const float* dt_bias = (const float*)d_in[6];
    const float* A_log   = (const float*)d_in[7];
    const float* D_skip  = (const float*)d_in[8];
    const float* W_out   = (const float*)d_in[9];
    float* out = (float*)d_out;

    float* ws   = (float*)d_ws;
    float* xT   = ws;                                        // 1280 x 4096 (x; then partials; then yN)
    float* gT   = xT   + (size_t)D_INNER * M_TOTAL;          // 1280 x 4096
    float* uT   = gT   + (size_t)D_INNER * M_TOTAL;          // 1280 x 4096 (u, then y in-place)
    float* xdbl = uT   + (size_t)D_INNER * M_TOTAL;          // 4096 x 108
    float* spT  = xdbl + (size_t)M_TOTAL * XDBL_W;           // 1280 x 4096
    float* rec  = spT  + (size_t)D_INNER * M_TOTAL;          // 2560*3*68 floats
    float* part = xT;                                        // 4*4096*108 partials (xT dead after conv)
    float* yN   = xT;                                        // 4096 x 1280 (partials dead after reduce)

    dim3 blk(256);

    // 1) merged in-proj: [xT; gT] = W_in @ hs^T  [2560][4096], silu rows>=1280
    gemm_mfma<2><<<dim3(M_TOTAL / 128, (2 * D_INNER) / 128), blk, 0, stream>>>(
        W_in, hs, xT, 2 * D_INNER, M_TOTAL, D_MODEL, D_MODEL, D_MODEL, M_TOTAL);

    // 2) u_T = silu(dwconv(x_T) + cb)     [1280][4096]
    conv_silu_kernel<<<(D_INNER * M_TOTAL + 255) / 256, blk, 0, stream>>>(
        xT, conv_w, conv_b, uT);

    // 3) x_dbl split-K partials -> [4096][108] (B/C coalesced across lanes)
    gemm_splitk<<<dim3((XDBL_W + BN - 1) / BN, M_TOTAL / BM, 4), blk, 0, stream>>>(
        uT, W_x, part, M_TOTAL, XDBL_W, D_INNER, M_TOTAL, D_INNER, XDBL_W);

    // 3b) xdbl = sum of 4 partials
    reduce4_kernel<<<(M_TOTAL * XDBL_W / 4 + 255) / 256, blk, 0, stream>>>(
        part, xdbl, M_TOTAL * XDBL_W);

    // 4) sp_T = softplus(W_dt @ dt_raw^T + bias)  [1280][4096]
    gemm_tn<0, 2><<<dim3(M_TOTAL / BN, D_INNER / BM), blk, 0, stream>>>(
        W_dt, xdbl, spT, D_INNER, M_TOTAL, DT_RANK, DT_RANK, XDBL_W, M_TOTAL,
        dt_bias);

    // 5a) chunk-local (h_end, P) for chunks 0..2   (2560 blocks x 3 waves)
    scan_part1<<<BATCH * D_INNER, 192, 0, stream>>>(
        xdbl, spT, A_log, uT, rec);

    // 5b) per-chunk y scan with combined h_start   (2560 blocks x 4 waves)
    scan_part3<<<BATCH * D_INNER, 256, 0, stream>>>(
        gT, xdbl, spT, A_log, D_skip, rec, uT);

    // 5c) transpose y: uT [1280][4096] -> yN [4096][1280]
    transpose_kernel<<<dim3(M_TOTAL / 32, D_INNER / 32), blk, 0, stream>>>(uT, yN);

    // 6) out = y @ W_out^T                [4096][640]   (split-bf16 MFMA)
    gemm_mfma<0><<<dim3(D_MODEL / 128, M_TOTAL / 128), blk, 0, stream>>>(
        yN, W_out, out, M_TOTAL, D_MODEL, D_INNER, D_INNER, D_INNER, D_MODEL);
}

// Round 22
// 558.183 us; speedup vs baseline: 1.0503x; 1.0503x over previous
//
#include <hip/hip_runtime.h>
#include <hip/hip_bf16.h>

#define D_MODEL   640
#define D_INNER   1280
#define D_STATE   34
#define D_CONV    4
#define DT_RANK   40
#define BATCH     2
#define SEQ       2048
#define XDBL_W    (DT_RANK + 2 * D_STATE)   // 108
#define M_TOTAL   (BATCH * SEQ)             // 4096
#define NCHUNK    4
#define CHLEN     (SEQ / NCHUNK)            // 512
#define RECW      68                        // record: 34 h_end + 34 P
#define PF        8

typedef __attribute__((ext_vector_type(8))) short short8v;   // bf16x8 (4 VGPR)
typedef __attribute__((ext_vector_type(4))) short short4v;   // bf16x4
typedef __attribute__((ext_vector_type(4))) float f32x4;     // MFMA acc

// Split f32 into bf16 hi (truncation) + bf16 lo (RNE of residual).
__device__ __forceinline__ void split_bf16(float x, short& hi, short& lo) {
    unsigned u  = __builtin_bit_cast(unsigned, x);
    unsigned uh = u & 0xFFFF0000u;
    hi = (short)(uh >> 16);
    float r = x - __builtin_bit_cast(float, uh);   // exact
    unsigned v = __builtin_bit_cast(unsigned, r);
    v += 0x7FFFu + ((v >> 16) & 1u);               // RNE to bf16
    lo = (short)(v >> 16);
}

// ---------------------------------------------------------------------------
// Pre-split f32 array into bf16 hi/lo arrays (grid-stride, float4 wide).
// ---------------------------------------------------------------------------
__global__ __launch_bounds__(256) void split_kernel(
    const float* __restrict__ in, short* __restrict__ hi,
    short* __restrict__ lo, int n)
{
    int i4 = (blockIdx.x * 256 + threadIdx.x) * 4;
    if (i4 >= n) return;
    float4 v = *reinterpret_cast<const float4*>(&in[i4]);
    short4v h, l;
    float xs[4] = {v.x, v.y, v.z, v.w};
    #pragma unroll
    for (int j = 0; j < 4; ++j) { short hh, ll; split_bf16(xs[j], hh, ll); h[j] = hh; l[j] = ll; }
    *reinterpret_cast<short4v*>(&hi[i4]) = h;
    *reinterpret_cast<short4v*>(&lo[i4]) = l;
}

// ---------------------------------------------------------------------------
// Split-bf16 MFMA GEMM on PRE-SPLIT operands:
// C[M,N] = (Ahi+Alo)[M,K] . (Bhi+Blo)[N,K]^T, 3-term MFMA.
// 128x128 tile, 256 threads (4 waves, 64x64), BK=32, bf16 short8 staging.
// MODE: 0 = none, 2 = silu(v) for output rows >= D_INNER (merged in-proj)
// ---------------------------------------------------------------------------
template<int MODE>
__global__ __launch_bounds__(256) void gemm_mfma_bf16(
    const short* __restrict__ Ahi, const short* __restrict__ Alo,
    const short* __restrict__ Bhi, const short* __restrict__ Blo,
    float* __restrict__ C, int M, int N, int K, int lda, int ldb, int ldc)
{
    constexpr int BMt = 128, BKt = 32;
    constexpr int LDT = 40;                        // LDS row stride in shorts
    __shared__ short As_hi[BMt * LDT], As_lo[BMt * LDT];
    __shared__ short Bs_hi[BMt * LDT], Bs_lo[BMt * LDT];

    const int tid  = threadIdx.x;
    const long m0  = (long)blockIdx.y * BMt;
    const long n0  = (long)blockIdx.x * BMt;
    const int wid  = tid >> 6, lane = tid & 63;
    const int wr   = (wid >> 1) * 64;
    const int wc   = (wid & 1) * 64;
    const int lrow = lane & 15;
    const int lkb  = lane >> 4;

    const bool do_silu = (MODE == 2) && (m0 >= D_INNER);   // block-uniform

    f32x4 acc[4][4] = {};

    for (int k0 = 0; k0 < K; k0 += BKt) {
        __syncthreads();
        // stage 128x32 bf16 tiles: 512 short8 per array, 2 per thread
        #pragma unroll
        for (int q = 0; q < 2; ++q) {
            int flat = tid + q * 256;              // 0..511
            int r  = flat >> 2;                    // 0..127
            int k8 = (flat & 3) * 8;               // 0,8,16,24
            *reinterpret_cast<short8v*>(&As_hi[r * LDT + k8]) =
                *reinterpret_cast<const short8v*>(&Ahi[(m0 + r) * lda + k0 + k8]);
            *reinterpret_cast<short8v*>(&As_lo[r * LDT + k8]) =
                *reinterpret_cast<const short8v*>(&Alo[(m0 + r) * lda + k0 + k8]);
            *reinterpret_cast<short8v*>(&Bs_hi[r * LDT + k8]) =
                *reinterpret_cast<const short8v*>(&Bhi[(n0 + r) * ldb + k0 + k8]);
            *reinterpret_cast<short8v*>(&Bs_lo[r * LDT + k8]) =
                *reinterpret_cast<const short8v*>(&Blo[(n0 + r) * ldb + k0 + k8]);
        }
        __syncthreads();

        short8v a_hi[4], a_lo[4], b_hi[4], b_lo[4];
        #pragma unroll
        for (int i = 0; i < 4; ++i) {
            int ar = (wr + i * 16 + lrow) * LDT + lkb * 8;
            int br = (wc + i * 16 + lrow) * LDT + lkb * 8;
            a_hi[i] = *reinterpret_cast<const short8v*>(&As_hi[ar]);
            a_lo[i] = *reinterpret_cast<const short8v*>(&As_lo[ar]);
            b_hi[i] = *reinterpret_cast<const short8v*>(&Bs_hi[br]);
            b_lo[i] = *reinterpret_cast<const short8v*>(&Bs_lo[br]);
        }
        #pragma unroll
        for (int i = 0; i < 4; ++i)
            #pragma unroll
            for (int j = 0; j < 4; ++j) {
                acc[i][j] = __builtin_amdgcn_mfma_f32_16x16x32_bf16(a_hi[i], b_hi[j], acc[i][j], 0, 0, 0);
                acc[i][j] = __builtin_amdgcn_mfma_f32_16x16x32_bf16(a_hi[i], b_lo[j], acc[i][j], 0, 0, 0);
                acc[i][j] = __builtin_amdgcn_mfma_f32_16x16x32_bf16(a_lo[i], b_hi[j], acc[i][j], 0, 0, 0);
            }
    }

    // D lane mapping: col = lane&15, row = (lane>>4)*4 + r   (m89/m91)
    #pragma unroll
    for (int i = 0; i < 4; ++i) {
        long grow0 = m0 + wr + i * 16 + lkb * 4;
        #pragma unroll
        for (int j = 0; j < 4; ++j) {
            long gcol = n0 + wc + j * 16 + lrow;
            #pragma unroll
            for (int r = 0; r < 4; ++r) {
                float v = acc[i][j][r];
                if (do_silu) v = v * (1.0f / (1.0f + __expf(-v)));
                C[(grow0 + r) * ldc + gcol] = v;
            }
        }
    }
}

// ---------------------------------------------------------------------------
// Small f32 GEMM. A [M,K] (LAYA=0) or [K,M] (LAYA=1); B [N,K] row-major.
// MODE: 0 = none, 2 = softplus(v + bias[gm]).
// ---------------------------------------------------------------------------
#define BM 64
#define BN 64
#define BK 16

template<int LAYA, int MODE>
__global__ __launch_bounds__(256) void gemm_tn(
    const float* __restrict__ A, const float* __restrict__ B,
    float* __restrict__ C, int M, int N, int K, int lda, int ldb, int ldc,
    const float* __restrict__ bias)
{
    __shared__ float As[BK][BM + 4];
    __shared__ float Bs[BK][BN + 4];

    const int tid = threadIdx.x;
    const int m0 = blockIdx.y * BM;
    const int n0 = blockIdx.x * BN;
    const int tx = tid & 15;
    const int ty = tid >> 4;

    float acc[4][4] = {};

    for (int k0 = 0; k0 < K; k0 += BK) {
        #pragma unroll
        for (int i = 0; i < 4; ++i) {
            int idx = tid + i * 256;
            if (LAYA == 0) {
                int r = idx >> 4;
                int c = idx & 15;
                As[c][r] = (m0 + r < M && k0 + c < K)
                         ? A[(long)(m0 + r) * lda + (k0 + c)] : 0.0f;
            } else {
                int c = idx >> 6;
                int r = idx & 63;
                As[c][r] = (m0 + r < M && k0 + c < K)
                         ? A[(long)(k0 + c) * lda + (m0 + r)] : 0.0f;
            }
            int rb = idx >> 4;
            int cb = idx & 15;
            Bs[cb][rb] = (n0 + rb < N && k0 + cb < K)
                       ? B[(long)(n0 + rb) * ldb + (k0 + cb)] : 0.0f;
        }
        __syncthreads();

        #pragma unroll
        for (int k = 0; k < BK; ++k) {
            const float4 a4 = *reinterpret_cast<const float4*>(&As[k][ty * 4]);
            const float4 b4 = *reinterpret_cast<const float4*>(&Bs[k][tx * 4]);
            const float a_[4] = {a4.x, a4.y, a4.z, a4.w};
            const float b_[4] = {b4.x, b4.y, b4.z, b4.w};
            #pragma unroll
            for (int i = 0; i < 4; ++i)
                #pragma unroll
                for (int j = 0; j < 4; ++j)
                    acc[i][j] = fmaf(a_[i], b_[j], acc[i][j]);
        }
        __syncthreads();
    }

    #pragma unroll
    for (int i = 0; i < 4; ++i) {
        int gm = m0 + ty * 4 + i;
        if (gm >= M) continue;
        float bi = (MODE == 2) ? bias[gm] : 0.0f;
        #pragma unroll
        for (int j = 0; j < 4; ++j) {
            int gn = n0 + tx * 4 + j;
            if (gn >= N) continue;
            float v = acc[i][j];
            if (MODE == 2) {
                v += bi;
                v = (v > 15.0f) ? v : log1pf(__expf(v));   // softplus
            }
            C[(long)gm * ldc + gn] = v;
        }
    }
}

// ---------------------------------------------------------------------------
// Split-K f32 GEMM for x_dbl (output [4096][108]): Cp[z] = A(K-slice).B^T.
// ---------------------------------------------------------------------------
__global__ __launch_bounds__(256) void gemm_splitk(
    const float* __restrict__ A, const float* __restrict__ B,
    float* __restrict__ Cp, int M, int N, int K, int lda, int ldb, int ldc)
{
    __shared__ float As[BK][BM + 4];
    __shared__ float Bs[BK][BN + 4];

    const int tid = threadIdx.x;
    const int m0 = blockIdx.y * BM;
    const int n0 = blockIdx.x * BN;
    const int z  = blockIdx.z;
    const int kseg = K / 4;
    const int kbeg = z * kseg;
    const int tx = tid & 15;
    const int ty = tid >> 4;

    float acc[4][4] = {};

    for (int k0 = kbeg; k0 < kbeg + kseg; k0 += BK) {
        #pragma unroll
        for (int i = 0; i < 4; ++i) {
            int idx = tid + i * 256;
            int c = idx >> 6;
            int r = idx & 63;
            As[c][r] = A[(long)(k0 + c) * lda + (m0 + r)];
            int rb = idx >> 4;
            int cb = idx & 15;
            Bs[cb][rb] = (n0 + rb < N) ? B[(long)(n0 + rb) * ldb + (k0 + cb)] : 0.0f;
        }
        __syncthreads();

        #pragma unroll
        for (int k = 0; k < BK; ++k) {
            const float4 a4 = *reinterpret_cast<const float4*>(&As[k][ty * 4]);
            const float4 b4 = *reinterpret_cast<const float4*>(&Bs[k][tx * 4]);
            const float a_[4] = {a4.x, a4.y, a4.z, a4.w};
            const float b_[4] = {b4.x, b4.y, b4.z, b4.w};
            #pragma unroll
            for (int i = 0; i < 4; ++i)
                #pragma unroll
                for (int j = 0; j < 4; ++j)
                    acc[i][j] = fmaf(a_[i], b_[j], acc[i][j]);
        }
        __syncthreads();
    }

    float* Cz = Cp + (long)z * M * ldc;
    #pragma unroll
    for (int i = 0; i < 4; ++i) {
        int gm = m0 + ty * 4 + i;
        #pragma unroll
        for (int j = 0; j < 4; ++j) {
            int gn = n0 + tx * 4 + j;
            if (gn < N) Cz[(long)gm * ldc + gn] = acc[i][j];
        }
    }
}

// Reduce 4 split-K partials.
__global__ __launch_bounds__(256) void reduce4_kernel(
    const float* __restrict__ part, float* __restrict__ out, int n)
{
    int i4 = (blockIdx.x * 256 + threadIdx.x) * 4;
    if (i4 >= n) return;
    float4 s0 = *reinterpret_cast<const float4*>(&part[i4]);
    float4 s1 = *reinterpret_cast<const float4*>(&part[(long)n + i4]);
    float4 s2 = *reinterpret_cast<const float4*>(&part[(long)2 * n + i4]);
    float4 s3 = *reinterpret_cast<const float4*>(&part[(long)3 * n + i4]);
    float4 r;
    r.x = (s0.x + s1.x) + (s2.x + s3.x);
    r.y = (s0.y + s1.y) + (s2.y + s3.y);
    r.z = (s0.z + s1.z) + (s2.z + s3.z);
    r.w = (s0.w + s1.w) + (s2.w + s3.w);
    *reinterpret_cast<float4*>(&out[i4]) = r;
}

// ---------------------------------------------------------------------------
// Depthwise causal conv (width 4) + bias + SiLU on TRANSPOSED x [1280][4096].
// ---------------------------------------------------------------------------
__global__ __launch_bounds__(256) void conv_silu_kernel(
    const float* __restrict__ xT, const float* __restrict__ cw,
    const float* __restrict__ cb, float* __restrict__ uT)
{
    int idx = blockIdx.x * 256 + threadIdx.x;      // d*4096 + bs
    if (idx >= D_INNER * M_TOTAL) return;
    int bs = idx & (M_TOTAL - 1);
    int d  = idx >> 12;
    int s  = bs & (SEQ - 1);

    const float* xr = xT + idx;
    float acc = cb[d];
    #pragma unroll
    for (int k = 0; k < D_CONV; ++k) {
        int off = k - (D_CONV - 1);                // -3..0
        if (s + off >= 0)
            acc = fmaf(xr[off], cw[d * D_CONV + k], acc);
    }
    uT[idx] = acc * (1.0f / (1.0f + __expf(-acc)));
}

// ---------------------------------------------------------------------------
// Transpose + split: uT [1280][4096] f32 -> yNhi/yNlo [4096][1280] bf16.
// ---------------------------------------------------------------------------
__global__ __launch_bounds__(256) void transpose_split_kernel(
    const float* __restrict__ in, short* __restrict__ hi, short* __restrict__ lo)
{
    __shared__ float tile[32][33];
    const int tx = threadIdx.x & 31;
    const int ty = threadIdx.x >> 5;
    const int t0 = blockIdx.x * 32;
    const int d0 = blockIdx.y * 32;

    #pragma unroll
    for (int i = 0; i < 32; i += 8)
        tile[ty + i][tx] = in[(long)(d0 + ty + i) * M_TOTAL + t0 + tx];
    __syncthreads();
    #pragma unroll
    for (int i = 0; i < 32; i += 8) {
        float v = tile[tx][ty + i];
        short hh, ll;
        split_bf16(v, hh, ll);
        long o = (long)(t0 + ty + i) * D_INNER + d0 + tx;
        hi[o] = hh;
        lo[o] = ll;
    }
}

#define DPP_ADD(X_, CTRL_) {                                                 \
        int t_ = __builtin_amdgcn_update_dpp(                                \
            0, __builtin_bit_cast(int, X_), (CTRL_), 0xf, 0xf, true);        \
        X_ += __builtin_bit_cast(float, t_);                                 \
    }

// ---------------------------------------------------------------------------
// Chunked scan pass 1 (r20-proven): chunk-local (h_end, P), one-wave blocks,
// scalar PF=8 FIFO, B from non-transposed xdbl (coalesced across lanes).
// ---------------------------------------------------------------------------
__global__ __launch_bounds__(64) void scan_part1(
    const float* __restrict__ xdbl,    // B at [bs*108 + 40 + n]
    const float* __restrict__ spT,     // softplus(dt+bias)[1280][4096]
    const float* __restrict__ A_log,
    const float* __restrict__ uT,      // u [1280][4096]
    float* __restrict__ rec)
{
    const int cid  = blockIdx.x;                   // bd*(NCHUNK-1) + c
    const int bd   = cid / (NCHUNK - 1);
    const int c    = cid % (NCHUNK - 1);
    const int lane = threadIdx.x;
    const int b = bd / D_INNER;
    const int d = bd % D_INNER;
    const bool act = lane < D_STATE;

    const float A_n = act ? -__expf(A_log[d * D_STATE + lane]) : 0.0f;

    const long base = (long)d * M_TOTAL + (long)b * SEQ + (long)c * CHLEN;
    const float* sp_p = spT + base;
    const float* u_p  = uT  + base;
    const float* bc_p = xdbl + ((long)b * SEQ + (long)c * CHLEN) * XDBL_W;

    float h = 0.0f, P = 1.0f;

    float aSP[PF], aU[PF], aB[PF];
    float bSP[PF], bU[PF], bB[PF];

#define LOADS1(SP_, U_, B_, T_) {                                            \
        int tt = (T_); tt = (tt < CHLEN) ? tt : (CHLEN - 1);                 \
        SP_ = sp_p[tt];                                                      \
        U_  = u_p [tt];                                                      \
        B_  = act ? bc_p[(long)tt * XDBL_W + DT_RANK + lane] : 0.0f;         \
    }

#define STEP1(SP_, U_, B_) {                                                 \
        float dA = __expf(SP_ * A_n);                                        \
        h = fmaf(dA, h, (SP_ * U_) * B_);                                    \
        P *= dA;                                                             \
    }

    #pragma unroll
    for (int i = 0; i < PF; ++i) LOADS1(aSP[i], aU[i], aB[i], i);

    for (int t0 = 0; t0 < CHLEN; t0 += 2 * PF) {
        #pragma unroll
        for (int i = 0; i < PF; ++i) LOADS1(bSP[i], bU[i], bB[i], t0 + PF + i);
        #pragma unroll
        for (int i = 0; i < PF; ++i) STEP1(aSP[i], aU[i], aB[i]);
        #pragma unroll
        for (int i = 0; i < PF; ++i) LOADS1(aSP[i], aU[i], aB[i], t0 + 2 * PF + i);
        #pragma unroll
        for (int i = 0; i < PF; ++i) STEP1(bSP[i], bU[i], bB[i]);
    }
#undef LOADS1
#undef STEP1

    if (act) {
        rec[(long)cid * RECW + lane]      = h;
        rec[(long)cid * RECW + 34 + lane] = P;
    }
}

// ---------------------------------------------------------------------------
// Chunked scan pass 3 (r20-proven): per-chunk y scan; h_start prologue;
// one-wave blocks; scalar PF=8 FIFO; B/C from non-transposed xdbl.
// ---------------------------------------------------------------------------
__global__ __launch_bounds__(64) void scan_part3(
    const float* __restrict__ gT,      // silu(z)          [1280][4096]
    const float* __restrict__ xdbl,    // B/C at [bs*108 + 40(+34) + n]
    const float* __restrict__ spT,     // softplus(dt+bias)[1280][4096]
    const float* __restrict__ A_log,
    const float* __restrict__ D_skip,
    const float* __restrict__ rec,
    float* __restrict__ uT)            // in: u, out: y*g (in-place)
{
    const int cid  = blockIdx.x;                   // bd*NCHUNK + c
    const int bd   = cid >> 2;
    const int c    = cid & (NCHUNK - 1);
    const int lane = threadIdx.x;
    const int b = bd / D_INNER;
    const int d = bd % D_INNER;
    const bool act = lane < D_STATE;

    const float A_n = act ? -__expf(A_log[d * D_STATE + lane]) : 0.0f;
    const float Dd  = D_skip[d];

    const long base = (long)d * M_TOTAL + (long)b * SEQ + (long)c * CHLEN;
    const float* sp_p = spT + base;
    const float* g_p  = gT  + base;
    float*       u_p  = uT  + base;
    const float* bc_p = xdbl + ((long)b * SEQ + (long)c * CHLEN) * XDBL_W;

    // ---- combine prologue: h_start from preceding chunks' records
    float h = 0.0f;
    for (int cc = 0; cc < c; ++cc) {
        long rbase = ((long)bd * (NCHUNK - 1) + cc) * RECW;
        float he = act ? rec[rbase + lane]      : 0.0f;
        float Pp = act ? rec[rbase + 34 + lane] : 0.0f;
        h = fmaf(Pp, h, he);
    }

    float aSP[PF], aU[PF], aG[PF], aB[PF], aC[PF];
    float bSP[PF], bU[PF], bG[PF], bB[PF], bC[PF];

#define LOADS(SP_, U_, G_, B_, C_, T_) {                                     \
        int tt = (T_); tt = (tt < CHLEN) ? tt : (CHLEN - 1);                 \
        SP_ = sp_p[tt];                                                      \
        U_  = u_p [tt];                                                      \
        G_  = g_p [tt];                                                      \
        const float* bcq = bc_p + (long)tt * XDBL_W + DT_RANK + lane;        \
        B_ = act ? bcq[0]       : 0.0f;                                      \
        C_ = act ? bcq[D_STATE] : 0.0f;                                      \
    }

#define STEP(SP_, U_, G_, B_, C_, T_) {                                      \
        float dA = __expf(SP_ * A_n);                                        \
        h = fmaf(dA, h, (SP_ * U_) * B_);                                    \
        float pp = h * C_;                                                   \
        DPP_ADD(pp, 0x111);   /* row_shr:1  */                               \
        DPP_ADD(pp, 0x112);   /* row_shr:2  */                               \
        DPP_ADD(pp, 0x114);   /* row_shr:4  */                               \
        DPP_ADD(pp, 0x118);   /* row_shr:8  */                               \
        DPP_ADD(pp, 0x142);   /* row_bcast:15 */                             \
        DPP_ADD(pp, 0x143);   /* row_bcast:31 */                             \
        if (lane == 63) {                                                    \
            float y = fmaf(U_, Dd, pp);                                      \
            u_p[T_] = y * G_;                                                \
        }                                                                    \
    }

    #pragma unroll
    for (int i = 0; i < PF; ++i) LOADS(aSP[i], aU[i], aG[i], aB[i], aC[i], i);

    for (int t0 = 0; t0 < CHLEN; t0 += 2 * PF) {
        #pragma unroll
        for (int i = 0; i < PF; ++i)
            LOADS(bSP[i], bU[i], bG[i], bB[i], bC[i], t0 + PF + i);
        #pragma unroll
        for (int i = 0; i < PF; ++i)
            STEP(aSP[i], aU[i], aG[i], aB[i], aC[i], t0 + i);
        #pragma unroll
        for (int i = 0; i < PF; ++i)
            LOADS(aSP[i], aU[i], aG[i], aB[i], aC[i], t0 + 2 * PF + i);
        #pragma unroll
        for (int i = 0; i < PF; ++i)
            STEP(bSP[i], bU[i], bG[i], bB[i], bC[i], t0 + PF + i);
    }
#undef LOADS
#undef STEP
}

// ---------------------------------------------------------------------------
extern "C" void kernel_launch(void* const* d_in, const int* in_sizes, int n_in,
                              void* d_out, int out_size, void* d_ws, size_t ws_size,
                              hipStream_t stream)
{
    const float* hs      = (const float*)d_in[0];
    const float* W_in    = (const float*)d_in[1];
    const float* conv_w  = (const float*)d_in[2];
    const float* conv_b  = (const float*)d_in[3];
    const float* W_x     = (const float*)d_in[4];
    const float* W_dt    = (const float*)d_in[5];
    const float* dt_bias = (const float*)d_in[6];
    const float* A_log   = (const float*)d_in[7];
    const float* D_skip  = (const float*)d_in[8];
    const float* W_out   = (const float*)d_in[9];
    float* out = (float*)d_out;

    float* ws   = (float*)d_ws;
    float* xT   = ws;                                        // 1280 x 4096 (x; then partials; then yN hi/lo)
    float* gT   = xT   + (size_t)D_INNER * M_TOTAL;          // 1280 x 4096 (g; then W_out hi/lo)
    float* uT   = gT   + (size_t)D_INNER * M_TOTAL;          // 1280 x 4096 (u, then y in-place)
    float* xdbl = uT   + (size_t)D_INNER * M_TOTAL;          // 4096 x 108
    float* spT  = xdbl + (size_t)M_TOTAL * XDBL_W;           // 1280 x 4096 (pre-split W_in/hs; then sp)
    float* rec  = spT  + (size_t)D_INNER * M_TOTAL;          // 2560*3*68 floats
    float* part = xT;                                        // 4*4096*108 partials (xT dead after conv)

    // bf16 hi/lo aliases (dead-region reuse):
    const int nW  = 2 * D_INNER * D_MODEL;                   // 1,638,400 (W_in)
    const int nH  = M_TOTAL * D_MODEL;                       // 2,621,440 (hs)
    const int nWO = D_MODEL * D_INNER;                       // 819,200  (W_out)
    short* Whi = (short*)spT;                                // in spT region (dead until dt-GEMM)
    short* Wlo = Whi + nW;
    short* Hhi = Wlo + nW;
    short* Hlo = Hhi + nH;                                   // total 17 MB < 21 MB region
    short* WOhi = (short*)gT;                                // gT dead after scan
    short* WOlo = WOhi + nWO;
    short* yNhi = (short*)xT;                                // xT dead after conv/reduce
    short* yNlo = yNhi + (size_t)M_TOTAL * D_INNER;          // 21 MB total = xT region

    dim3 blk(256);

    // 0) pre-split W_in and hs into bf16 hi/lo (spT region)
    split_kernel<<<(nW / 4 + 255) / 256, blk, 0, stream>>>(W_in, Whi, Wlo, nW);
    split_kernel<<<(nH / 4 + 255) / 256, blk, 0, stream>>>(hs, Hhi, Hlo, nH);

    // 1) merged in-proj: [xT; gT] = W_in @ hs^T  [2560][4096], silu rows>=1280
    gemm_mfma_bf16<2><<<dim3(M_TOTAL / 128, (2 * D_INNER) / 128), blk, 0, stream>>>(
        Whi, Wlo, Hhi, Hlo, xT, 2 * D_INNER, M_TOTAL, D_MODEL,
        D_MODEL, D_MODEL, M_TOTAL);

    // 2) u_T = silu(dwconv(x_T) + cb)     [1280][4096]
    conv_silu_kernel<<<(D_INNER * M_TOTAL + 255) / 256, blk, 0, stream>>>(
        xT, conv_w, conv_b, uT);

    // 3) x_dbl split-K partials -> [4096][108]
    gemm_splitk<<<dim3((XDBL_W + BN - 1) / BN, M_TOTAL / BM, 4), blk, 0, stream>>>(
        uT, W_x, part, M_TOTAL, XDBL_W, D_INNER, M_TOTAL, D_INNER, XDBL_W);

    // 3b) xdbl = sum of 4 partials
    reduce4_kernel<<<(M_TOTAL * XDBL_W / 4 + 255) / 256, blk, 0, stream>>>(
        part, xdbl, M_TOTAL * XDBL_W);

    // 4) sp_T = softplus(W_dt @ dt_raw^T + bias)  [1280][4096]
    //    (overwrites the pre-split W_in/hs buffers -- they are dead now)
    gemm_tn<0, 2><<<dim3(M_TOTAL / BN, D_INNER / BM), blk, 0, stream>>>(
        W_dt, xdbl, spT, D_INNER, M_TOTAL, DT_RANK, DT_RANK, XDBL_W, M_TOTAL,
        dt_bias);

    // 5a) chunk-local (h_end, P) for chunks 0..2   (2560*3 one-wave blocks)
    scan_part1<<<BATCH * D_INNER * (NCHUNK - 1), 64, 0, stream>>>(
        xdbl, spT, A_log, uT, rec);

    // 5b) per-chunk y scan with combined h_start   (2560*4 one-wave blocks)
    scan_part3<<<BATCH * D_INNER * NCHUNK, 64, 0, stream>>>(
        gT, xdbl, spT, A_log, D_skip, rec, uT);

    // 5c) split W_out (gT region, g is dead after scan)
    split_kernel<<<(nWO / 4 + 255) / 256, blk, 0, stream>>>(W_out, WOhi, WOlo, nWO);

    // 5d) transpose+split y: uT [1280][4096] -> yNhi/yNlo [4096][1280] bf16
    transpose_split_kernel<<<dim3(M_TOTAL / 32, D_INNER / 32), blk, 0, stream>>>(
        uT, yNhi, yNlo);

    // 6) out = y @ W_out^T                [4096][640]   (pre-split MFMA)
    gemm_mfma_bf16<0><<<dim3(D_MODEL / 128, M_TOTAL / 128), blk, 0, stream>>>(
        yNhi, yNlo, WOhi, WOlo, out, M_TOTAL, D_MODEL, D_INNER,
        D_INNER, D_INNER, D_MODEL);
}

// Round 24
// 551.283 us; speedup vs baseline: 1.0635x; 1.0125x over previous
//
#include <hip/hip_runtime.h>
#include <hip/hip_bf16.h>

#define D_MODEL   640
#define D_INNER   1280
#define D_STATE   34
#define D_CONV    4
#define DT_RANK   40
#define BATCH     2
#define SEQ       2048
#define XDBL_W    (DT_RANK + 2 * D_STATE)   // 108
#define M_TOTAL   (BATCH * SEQ)             // 4096
#define NCHUNK    4
#define CHLEN     (SEQ / NCHUNK)            // 512
#define RECW      68                        // record: 34 h_end + 34 P
#define PF        8

typedef __attribute__((ext_vector_type(8))) short short8v;   // bf16x8 (4 VGPR)
typedef __attribute__((ext_vector_type(4))) short short4v;   // bf16x4
typedef __attribute__((ext_vector_type(4))) float f32x4;     // MFMA acc

// Split f32 into bf16 hi (truncation) + bf16 lo (RNE of residual).
__device__ __forceinline__ void split_bf16(float x, short& hi, short& lo) {
    unsigned u  = __builtin_bit_cast(unsigned, x);
    unsigned uh = u & 0xFFFF0000u;
    hi = (short)(uh >> 16);
    float r = x - __builtin_bit_cast(float, uh);   // exact
    unsigned v = __builtin_bit_cast(unsigned, r);
    v += 0x7FFFu + ((v >> 16) & 1u);               // RNE to bf16
    lo = (short)(v >> 16);
}

// ---------------------------------------------------------------------------
// Pre-split f32 array into bf16 hi/lo arrays (float4 wide).
// ---------------------------------------------------------------------------
__global__ __launch_bounds__(256) void split_kernel(
    const float* __restrict__ in, short* __restrict__ hi,
    short* __restrict__ lo, int n)
{
    int i4 = (blockIdx.x * 256 + threadIdx.x) * 4;
    if (i4 >= n) return;
    float4 v = *reinterpret_cast<const float4*>(&in[i4]);
    short4v h, l;
    float xs[4] = {v.x, v.y, v.z, v.w};
    #pragma unroll
    for (int j = 0; j < 4; ++j) { short hh, ll; split_bf16(xs[j], hh, ll); h[j] = hh; l[j] = ll; }
    *reinterpret_cast<short4v*>(&hi[i4]) = h;
    *reinterpret_cast<short4v*>(&lo[i4]) = l;
}

// ---------------------------------------------------------------------------
// Split-bf16 MFMA GEMM on PRE-SPLIT operands:
// C[M,N] = (Ahi+Alo)[M,K] . (Bhi+Blo)[N,K]^T, 3-term MFMA.
// MODE: 0 = none, 2 = silu(v) for output rows >= D_INNER (merged in-proj)
// ---------------------------------------------------------------------------
template<int MODE>
__global__ __launch_bounds__(256) void gemm_mfma_bf16(
    const short* __restrict__ Ahi, const short* __restrict__ Alo,
    const short* __restrict__ Bhi, const short* __restrict__ Blo,
    float* __restrict__ C, int M, int N, int K, int lda, int ldb, int ldc)
{
    constexpr int BMt = 128, BKt = 32;
    constexpr int LDT = 40;                        // LDS row stride in shorts
    __shared__ short As_hi[BMt * LDT], As_lo[BMt * LDT];
    __shared__ short Bs_hi[BMt * LDT], Bs_lo[BMt * LDT];

    const int tid  = threadIdx.x;
    const long m0  = (long)blockIdx.y * BMt;
    const long n0  = (long)blockIdx.x * BMt;
    const int wid  = tid >> 6, lane = tid & 63;
    const int wr   = (wid >> 1) * 64;
    const int wc   = (wid & 1) * 64;
    const int lrow = lane & 15;
    const int lkb  = lane >> 4;

    const bool do_silu = (MODE == 2) && (m0 >= D_INNER);   // block-uniform

    f32x4 acc[4][4] = {};

    for (int k0 = 0; k0 < K; k0 += BKt) {
        __syncthreads();
        #pragma unroll
        for (int q = 0; q < 2; ++q) {
            int flat = tid + q * 256;              // 0..511
            int r  = flat >> 2;                    // 0..127
            int k8 = (flat & 3) * 8;               // 0,8,16,24
            *reinterpret_cast<short8v*>(&As_hi[r * LDT + k8]) =
                *reinterpret_cast<const short8v*>(&Ahi[(m0 + r) * lda + k0 + k8]);
            *reinterpret_cast<short8v*>(&As_lo[r * LDT + k8]) =
                *reinterpret_cast<const short8v*>(&Alo[(m0 + r) * lda + k0 + k8]);
            *reinterpret_cast<short8v*>(&Bs_hi[r * LDT + k8]) =
                *reinterpret_cast<const short8v*>(&Bhi[(n0 + r) * ldb + k0 + k8]);
            *reinterpret_cast<short8v*>(&Bs_lo[r * LDT + k8]) =
                *reinterpret_cast<const short8v*>(&Blo[(n0 + r) * ldb + k0 + k8]);
        }
        __syncthreads();

        short8v a_hi[4], a_lo[4], b_hi[4], b_lo[4];
        #pragma unroll
        for (int i = 0; i < 4; ++i) {
            int ar = (wr + i * 16 + lrow) * LDT + lkb * 8;
            int br = (wc + i * 16 + lrow) * LDT + lkb * 8;
            a_hi[i] = *reinterpret_cast<const short8v*>(&As_hi[ar]);
            a_lo[i] = *reinterpret_cast<const short8v*>(&As_lo[ar]);
            b_hi[i] = *reinterpret_cast<const short8v*>(&Bs_hi[br]);
            b_lo[i] = *reinterpret_cast<const short8v*>(&Bs_lo[br]);
        }
        #pragma unroll
        for (int i = 0; i < 4; ++i)
            #pragma unroll
            for (int j = 0; j < 4; ++j) {
                acc[i][j] = __builtin_amdgcn_mfma_f32_16x16x32_bf16(a_hi[i], b_hi[j], acc[i][j], 0, 0, 0);
                acc[i][j] = __builtin_amdgcn_mfma_f32_16x16x32_bf16(a_hi[i], b_lo[j], acc[i][j], 0, 0, 0);
                acc[i][j] = __builtin_amdgcn_mfma_f32_16x16x32_bf16(a_lo[i], b_hi[j], acc[i][j], 0, 0, 0);
            }
    }

    // D lane mapping: col = lane&15, row = (lane>>4)*4 + r   (m89/m91)
    #pragma unroll
    for (int i = 0; i < 4; ++i) {
        long grow0 = m0 + wr + i * 16 + lkb * 4;
        #pragma unroll
        for (int j = 0; j < 4; ++j) {
            long gcol = n0 + wc + j * 16 + lrow;
            #pragma unroll
            for (int r = 0; r < 4; ++r) {
                float v = acc[i][j][r];
                if (do_silu) v = v * (1.0f / (1.0f + __expf(-v)));
                C[(grow0 + r) * ldc + gcol] = v;
            }
        }
    }
}

// ---------------------------------------------------------------------------
// Small f32 GEMM. A [M,K] (LAYA=0) or [K,M] (LAYA=1); B [N,K] row-major.
// MODE: 0 = none, 2 = softplus(v + bias[gm]).
// ---------------------------------------------------------------------------
#define BM 64
#define BN 64
#define BK 16

template<int LAYA, int MODE>
__global__ __launch_bounds__(256) void gemm_tn(
    const float* __restrict__ A, const float* __restrict__ B,
    float* __restrict__ C, int M, int N, int K, int lda, int ldb, int ldc,
    const float* __restrict__ bias)
{
    __shared__ float As[BK][BM + 4];
    __shared__ float Bs[BK][BN + 4];

    const int tid = threadIdx.x;
    const int m0 = blockIdx.y * BM;
    const int n0 = blockIdx.x * BN;
    const int tx = tid & 15;
    const int ty = tid >> 4;

    float acc[4][4] = {};

    for (int k0 = 0; k0 < K; k0 += BK) {
        #pragma unroll
        for (int i = 0; i < 4; ++i) {
            int idx = tid + i * 256;
            if (LAYA == 0) {
                int r = idx >> 4;
                int c = idx & 15;
                As[c][r] = (m0 + r < M && k0 + c < K)
                         ? A[(long)(m0 + r) * lda + (k0 + c)] : 0.0f;
            } else {
                int c = idx >> 6;
                int r = idx & 63;
                As[c][r] = (m0 + r < M && k0 + c < K)
                         ? A[(long)(k0 + c) * lda + (m0 + r)] : 0.0f;
            }
            int rb = idx >> 4;
            int cb = idx & 15;
            Bs[cb][rb] = (n0 + rb < N && k0 + cb < K)
                       ? B[(long)(n0 + rb) * ldb + (k0 + cb)] : 0.0f;
        }
        __syncthreads();

        #pragma unroll
        for (int k = 0; k < BK; ++k) {
            const float4 a4 = *reinterpret_cast<const float4*>(&As[k][ty * 4]);
            const float4 b4 = *reinterpret_cast<const float4*>(&Bs[k][tx * 4]);
            const float a_[4] = {a4.x, a4.y, a4.z, a4.w};
            const float b_[4] = {b4.x, b4.y, b4.z, b4.w};
            #pragma unroll
            for (int i = 0; i < 4; ++i)
                #pragma unroll
                for (int j = 0; j < 4; ++j)
                    acc[i][j] = fmaf(a_[i], b_[j], acc[i][j]);
        }
        __syncthreads();
    }

    #pragma unroll
    for (int i = 0; i < 4; ++i) {
        int gm = m0 + ty * 4 + i;
        if (gm >= M) continue;
        float bi = (MODE == 2) ? bias[gm] : 0.0f;
        #pragma unroll
        for (int j = 0; j < 4; ++j) {
            int gn = n0 + tx * 4 + j;
            if (gn >= N) continue;
            float v = acc[i][j];
            if (MODE == 2) {
                v += bi;
                v = (v > 15.0f) ? v : log1pf(__expf(v));   // softplus
            }
            C[(long)gm * ldc + gn] = v;
        }
    }
}

// ---------------------------------------------------------------------------
// Split-K f32 GEMM for x_dbl (output [4096][108]): Cp[z] = A(K-slice).B^T.
// ---------------------------------------------------------------------------
__global__ __launch_bounds__(256) void gemm_splitk(
    const float* __restrict__ A, const float* __restrict__ B,
    float* __restrict__ Cp, int M, int N, int K, int lda, int ldb, int ldc)
{
    __shared__ float As[BK][BM + 4];
    __shared__ float Bs[BK][BN + 4];

    const int tid = threadIdx.x;
    const int m0 = blockIdx.y * BM;
    const int n0 = blockIdx.x * BN;
    const int z  = blockIdx.z;
    const int kseg = K / 4;
    const int kbeg = z * kseg;
    const int tx = tid & 15;
    const int ty = tid >> 4;

    float acc[4][4] = {};

    for (int k0 = kbeg; k0 < kbeg + kseg; k0 += BK) {
        #pragma unroll
        for (int i = 0; i < 4; ++i) {
            int idx = tid + i * 256;
            int c = idx >> 6;
            int r = idx & 63;
            As[c][r] = A[(long)(k0 + c) * lda + (m0 + r)];
            int rb = idx >> 4;
            int cb = idx & 15;
            Bs[cb][rb] = (n0 + rb < N) ? B[(long)(n0 + rb) * ldb + (k0 + cb)] : 0.0f;
        }
        __syncthreads();

        #pragma unroll
        for (int k = 0; k < BK; ++k) {
            const float4 a4 = *reinterpret_cast<const float4*>(&As[k][ty * 4]);
            const float4 b4 = *reinterpret_cast<const float4*>(&Bs[k][tx * 4]);
            const float a_[4] = {a4.x, a4.y, a4.z, a4.w};
            const float b_[4] = {b4.x, b4.y, b4.z, b4.w};
            #pragma unroll
            for (int i = 0; i < 4; ++i)
                #pragma unroll
                for (int j = 0; j < 4; ++j)
                    acc[i][j] = fmaf(a_[i], b_[j], acc[i][j]);
        }
        __syncthreads();
    }

    float* Cz = Cp + (long)z * M * ldc;
    #pragma unroll
    for (int i = 0; i < 4; ++i) {
        int gm = m0 + ty * 4 + i;
        #pragma unroll
        for (int j = 0; j < 4; ++j) {
            int gn = n0 + tx * 4 + j;
            if (gn < N) Cz[(long)gm * ldc + gn] = acc[i][j];
        }
    }
}

// Reduce 4 split-K partials.
__global__ __launch_bounds__(256) void reduce4_kernel(
    const float* __restrict__ part, float* __restrict__ out, int n)
{
    int i4 = (blockIdx.x * 256 + threadIdx.x) * 4;
    if (i4 >= n) return;
    float4 s0 = *reinterpret_cast<const float4*>(&part[i4]);
    float4 s1 = *reinterpret_cast<const float4*>(&part[(long)n + i4]);
    float4 s2 = *reinterpret_cast<const float4*>(&part[(long)2 * n + i4]);
    float4 s3 = *reinterpret_cast<const float4*>(&part[(long)3 * n + i4]);
    float4 r;
    r.x = (s0.x + s1.x) + (s2.x + s3.x);
    r.y = (s0.y + s1.y) + (s2.y + s3.y);
    r.z = (s0.z + s1.z) + (s2.z + s3.z);
    r.w = (s0.w + s1.w) + (s2.w + s3.w);
    *reinterpret_cast<float4*>(&out[i4]) = r;
}

// ---------------------------------------------------------------------------
// Depthwise causal conv (width 4) + bias + SiLU, float4-vectorized over t.
// Each thread computes 4 consecutive outputs from cur/prev float4 window.
// ---------------------------------------------------------------------------
__global__ __launch_bounds__(256) void conv_silu_kernel(
    const float* __restrict__ xT, const float* __restrict__ cw,
    const float* __restrict__ cb, float* __restrict__ uT)
{
    int i4 = (blockIdx.x * 256 + threadIdx.x) * 4;   // d*4096 + p, p multiple of 4
    if (i4 >= D_INNER * M_TOTAL) return;
    int p = i4 & (M_TOTAL - 1);
    int d = i4 >> 12;
    int s = p & (SEQ - 1);                           // multiple of 4; ==0 at seq start

    float4 cur = *reinterpret_cast<const float4*>(&xT[i4]);
    float4 prev = make_float4(0.f, 0.f, 0.f, 0.f);
    if (s != 0) prev = *reinterpret_cast<const float4*>(&xT[i4 - 4]);

    const float w0 = cw[d * D_CONV + 0], w1 = cw[d * D_CONV + 1];
    const float w2 = cw[d * D_CONV + 2], w3 = cw[d * D_CONV + 3];
    const float bi = cb[d];

    // window: prev.y..prev.w = x[p-3..p-1]; cur = x[p..p+3]
    float o0 = bi, o1 = bi, o2 = bi, o3 = bi;
    o0 = fmaf(prev.y, w0, o0); o0 = fmaf(prev.z, w1, o0); o0 = fmaf(prev.w, w2, o0); o0 = fmaf(cur.x, w3, o0);
    o1 = fmaf(prev.z, w0, o1); o1 = fmaf(prev.w, w1, o1); o1 = fmaf(cur.x, w2, o1); o1 = fmaf(cur.y, w3, o1);
    o2 = fmaf(prev.w, w0, o2); o2 = fmaf(cur.x, w1, o2); o2 = fmaf(cur.y, w2, o2); o2 = fmaf(cur.z, w3, o2);
    o3 = fmaf(cur.x,  w0, o3); o3 = fmaf(cur.y, w1, o3); o3 = fmaf(cur.z, w2, o3); o3 = fmaf(cur.w, w3, o3);

    float4 r;
    r.x = o0 * (1.0f / (1.0f + __expf(-o0)));
    r.y = o1 * (1.0f / (1.0f + __expf(-o1)));
    r.z = o2 * (1.0f / (1.0f + __expf(-o2)));
    r.w = o3 * (1.0f / (1.0f + __expf(-o3)));
    *reinterpret_cast<float4*>(&uT[i4]) = r;
}

// ---------------------------------------------------------------------------
// Transpose + split: uT [1280][4096] f32 -> yNhi/yNlo [4096][1280] bf16.
// ---------------------------------------------------------------------------
__global__ __launch_bounds__(256) void transpose_split_kernel(
    const float* __restrict__ in, short* __restrict__ hi, short* __restrict__ lo)
{
    __shared__ float tile[32][33];
    const int tx = threadIdx.x & 31;
    const int ty = threadIdx.x >> 5;
    const int t0 = blockIdx.x * 32;
    const int d0 = blockIdx.y * 32;

    #pragma unroll
    for (int i = 0; i < 32; i += 8)
        tile[ty + i][tx] = in[(long)(d0 + ty + i) * M_TOTAL + t0 + tx];
    __syncthreads();
    #pragma unroll
    for (int i = 0; i < 32; i += 8) {
        float v = tile[tx][ty + i];
        short hh, ll;
        split_bf16(v, hh, ll);
        long o = (long)(t0 + ty + i) * D_INNER + d0 + tx;
        hi[o] = hh;
        lo[o] = ll;
    }
}

#define DPP_ADD(X_, CTRL_) {                                                 \
        int t_ = __builtin_amdgcn_update_dpp(                                \
            0, __builtin_bit_cast(int, X_), (CTRL_), 0xf, 0xf, true);        \
        X_ += __builtin_bit_cast(float, t_);                                 \
    }

// ---------------------------------------------------------------------------
// Chunked scan pass 1 (r20-proven): chunk-local (h_end, P), one-wave blocks,
// scalar PF=8 FIFO, B from non-transposed xdbl (coalesced across lanes).
// ---------------------------------------------------------------------------
__global__ __launch_bounds__(64) void scan_part1(
    const float* __restrict__ xdbl,    // B at [bs*108 + 40 + n]
    const float* __restrict__ spT,     // softplus(dt+bias)[1280][4096]
    const float* __restrict__ A_log,
    const float* __restrict__ uT,      // u [1280][4096]
    float* __restrict__ rec)
{
    const int cid  = blockIdx.x;                   // bd*(NCHUNK-1) + c
    const int bd   = cid / (NCHUNK - 1);
    const int c    = cid % (NCHUNK - 1);
    const int lane = threadIdx.x;
    const int b = bd / D_INNER;
    const int d = bd % D_INNER;
    const bool act = lane < D_STATE;

    const float A_n = act ? -__expf(A_log[d * D_STATE + lane]) : 0.0f;

    const long base = (long)d * M_TOTAL + (long)b * SEQ + (long)c * CHLEN;
    const float* sp_p = spT + base;
    const float* u_p  = uT  + base;
    const float* bc_p = xdbl + ((long)b * SEQ + (long)c * CHLEN) * XDBL_W;

    float h = 0.0f, P = 1.0f;

    float aSP[PF], aU[PF], aB[PF];
    float bSP[PF], bU[PF], bB[PF];

#define LOADS1(SP_, U_, B_, T_) {                                            \
        int tt = (T_); tt = (tt < CHLEN) ? tt : (CHLEN - 1);                 \
        SP_ = sp_p[tt];                                                      \
        U_  = u_p [tt];                                                      \
        B_  = act ? bc_p[(long)tt * XDBL_W + DT_RANK + lane] : 0.0f;         \
    }

#define STEP1(SP_, U_, B_) {                                                 \
        float dA = __expf(SP_ * A_n);                                        \
        h = fmaf(dA, h, (SP_ * U_) * B_);                                    \
        P *= dA;                                                             \
    }

    #pragma unroll
    for (int i = 0; i < PF; ++i) LOADS1(aSP[i], aU[i], aB[i], i);

    for (int t0 = 0; t0 < CHLEN; t0 += 2 * PF) {
        #pragma unroll
        for (int i = 0; i < PF; ++i) LOADS1(bSP[i], bU[i], bB[i], t0 + PF + i);
        #pragma unroll
        for (int i = 0; i < PF; ++i) STEP1(aSP[i], aU[i], aB[i]);
        #pragma unroll
        for (int i = 0; i < PF; ++i) LOADS1(aSP[i], aU[i], aB[i], t0 + 2 * PF + i);
        #pragma unroll
        for (int i = 0; i < PF; ++i) STEP1(bSP[i], bU[i], bB[i]);
    }
#undef LOADS1
#undef STEP1

    if (act) {
        rec[(long)cid * RECW + lane]      = h;
        rec[(long)cid * RECW + 34 + lane] = P;
    }
}

// ---------------------------------------------------------------------------
// Chunked scan pass 3 (r20-proven): per-chunk y scan; h_start prologue;
// one-wave blocks; scalar PF=8 FIFO; B/C from non-transposed xdbl.
// ---------------------------------------------------------------------------
__global__ __launch_bounds__(64) void scan_part3(
    const float* __restrict__ gT,      // silu(z)          [1280][4096]
    const float* __restrict__ xdbl,    // B/C at [bs*108 + 40(+34) + n]
    const float* __restrict__ spT,     // softplus(dt+bias)[1280][4096]
    const float* __restrict__ A_log,
    const float* __restrict__ D_skip,
    const float* __restrict__ rec,
    float* __restrict__ uT)            // in: u, out: y*g (in-place)
{
    const int cid  = blockIdx.x;                   // bd*NCHUNK + c
    const int bd   = cid >> 2;
    const int c    = cid & (NCHUNK - 1);
    const int lane = threadIdx.x;
    const int b = bd / D_INNER;
    const int d = bd % D_INNER;
    const bool act = lane < D_STATE;

    const float A_n = act ? -__expf(A_log[d * D_STATE + lane]) : 0.0f;
    const float Dd  = D_skip[d];

    const long base = (long)d * M_TOTAL + (long)b * SEQ + (long)c * CHLEN;
    const float* sp_p = spT + base;
    const float* g_p  = gT  + base;
    float*       u_p  = uT  + base;
    const float* bc_p = xdbl + ((long)b * SEQ + (long)c * CHLEN) * XDBL_W;

    // ---- combine prologue: h_start from preceding chunks' records
    float h = 0.0f;
    for (int cc = 0; cc < c; ++cc) {
        long rbase = ((long)bd * (NCHUNK - 1) + cc) * RECW;
        float he = act ? rec[rbase + lane]      : 0.0f;
        float Pp = act ? rec[rbase + 34 + lane] : 0.0f;
        h = fmaf(Pp, h, he);
    }

    float aSP[PF], aU[PF], aG[PF], aB[PF], aC[PF];
    float bSP[PF], bU[PF], bG[PF], bB[PF], bC[PF];

#define LOADS(SP_, U_, G_, B_, C_, T_) {                                     \
        int tt = (T_); tt = (tt < CHLEN) ? tt : (CHLEN - 1);                 \
        SP_ = sp_p[tt];                                                      \
        U_  = u_p [tt];                                                      \
        G_  = g_p [tt];                                                      \
        const float* bcq = bc_p + (long)tt * XDBL_W + DT_RANK + lane;        \
        B_ = act ? bcq[0]       : 0.0f;                                      \
        C_ = act ? bcq[D_STATE] : 0.0f;                                      \
    }

#define STEP(SP_, U_, G_, B_, C_, T_) {                                      \
        float dA = __expf(SP_ * A_n);                                        \
        h = fmaf(dA, h, (SP_ * U_) * B_);                                    \
        float pp = h * C_;                                                   \
        DPP_ADD(pp, 0x111);   /* row_shr:1  */                               \
        DPP_ADD(pp, 0x112);   /* row_shr:2  */                               \
        DPP_ADD(pp, 0x114);   /* row_shr:4  */                               \
        DPP_ADD(pp, 0x118);   /* row_shr:8  */                               \
        DPP_ADD(pp, 0x142);   /* row_bcast:15 */                             \
        DPP_ADD(pp, 0x143);   /* row_bcast:31 */                             \
        if (lane == 63) {                                                    \
            float y = fmaf(U_, Dd, pp);                                      \
            u_p[T_] = y * G_;                                                \
        }                                                                    \
    }

    #pragma unroll
    for (int i = 0; i < PF; ++i) LOADS(aSP[i], aU[i], aG[i], aB[i], aC[i], i);

    for (int t0 = 0; t0 < CHLEN; t0 += 2 * PF) {
        #pragma unroll
        for (int i = 0; i < PF; ++i)
            LOADS(bSP[i], bU[i], bG[i], bB[i], bC[i], t0 + PF + i);
        #pragma unroll
        for (int i = 0; i < PF; ++i)
            STEP(aSP[i], aU[i], aG[i], aB[i], aC[i], t0 + i);
        #pragma unroll
        for (int i = 0; i < PF; ++i)
            LOADS(aSP[i], aU[i], aG[i], aB[i], aC[i], t0 + 2 * PF + i);
        #pragma unroll
        for (int i = 0; i < PF; ++i)
            STEP(bSP[i], bU[i], bG[i], bB[i], bC[i], t0 + PF + i);
    }
#undef LOADS
#undef STEP
}

// ---------------------------------------------------------------------------
extern "C" void kernel_launch(void* const* d_in, const int* in_sizes, int n_in,
                              void* d_out, int out_size, void* d_ws, size_t ws_size,
                              hipStream_t stream)
{
    const float* hs      = (const float*)d_in[0];
    const float* W_in    = (const float*)d_in[1];
    const float* conv_w  = (const float*)d_in[2];
    const float* conv_b  = (const float*)d_in[3];
    const float* W_x     = (const float*)d_in[4];
    const float* W_dt    = (const float*)d_in[5];
    const float* dt_bias = (const float*)d_in[6];
    const float* A_log   = (const float*)d_in[7];
    const float* D_skip  = (const float*)d_in[8];
    const float* W_out   = (const float*)d_in[9];
    float* out = (float*)d_out;

    float* ws   = (float*)d_ws;
    float* xT   = ws;                                        // 1280 x 4096 (x; then partials; then yN hi/lo)
    float* gT   = xT   + (size_t)D_INNER * M_TOTAL;          // 1280 x 4096 (g; then W_out hi/lo)
    float* uT   = gT   + (size_t)D_INNER * M_TOTAL;          // 1280 x 4096 (u, then y in-place)
    float* xdbl = uT   + (size_t)D_INNER * M_TOTAL;          // 4096 x 108
    float* spT  = xdbl + (size_t)M_TOTAL * XDBL_W;           // 1280 x 4096 (pre-split W_in/hs; then sp)
    float* rec  = spT  + (size_t)D_INNER * M_TOTAL;          // 2560*3*68 floats
    float* part = xT;                                        // 4*4096*108 partials (xT dead after conv)

    // bf16 hi/lo aliases (dead-region reuse):
    const int nW  = 2 * D_INNER * D_MODEL;                   // 1,638,400 (W_in)
    const int nH  = M_TOTAL * D_MODEL;                       // 2,621,440 (hs)
    const int nWO = D_MODEL * D_INNER;                       // 819,200  (W_out)
    short* Whi = (short*)spT;                                // in spT region (dead until dt-GEMM)
    short* Wlo = Whi + nW;
    short* Hhi = Wlo + nW;
    short* Hlo = Hhi + nH;                                   // total 17 MB < 21 MB region
    short* WOhi = (short*)gT;                                // gT dead after scan
    short* WOlo = WOhi + nWO;
    short* yNhi = (short*)xT;                                // xT dead after conv/reduce
    short* yNlo = yNhi + (size_t)M_TOTAL * D_INNER;          // 21 MB total = xT region

    dim3 blk(256);

    // 0) pre-split W_in and hs into bf16 hi/lo (spT region)
    split_kernel<<<(nW / 4 + 255) / 256, blk, 0, stream>>>(W_in, Whi, Wlo, nW);
    split_kernel<<<(nH / 4 + 255) / 256, blk, 0, stream>>>(hs, Hhi, Hlo, nH);

    // 1) merged in-proj: [xT; gT] = W_in @ hs^T  [2560][4096], silu rows>=1280
    gemm_mfma_bf16<2><<<dim3(M_TOTAL / 128, (2 * D_INNER) / 128), blk, 0, stream>>>(
        Whi, Wlo, Hhi, Hlo, xT, 2 * D_INNER, M_TOTAL, D_MODEL,
        D_MODEL, D_MODEL, M_TOTAL);

    // 2) u_T = silu(dwconv(x_T) + cb)     [1280][4096]  (float4-vectorized)
    conv_silu_kernel<<<(D_INNER * M_TOTAL / 4 + 255) / 256, blk, 0, stream>>>(
        xT, conv_w, conv_b, uT);

    // 3) x_dbl split-K partials -> [4096][108]
    gemm_splitk<<<dim3((XDBL_W + BN - 1) / BN, M_TOTAL / BM, 4), blk, 0, stream>>>(
        uT, W_x, part, M_TOTAL, XDBL_W, D_INNER, M_TOTAL, D_INNER, XDBL_W);

    // 3b) xdbl = sum of 4 partials
    reduce4_kernel<<<(M_TOTAL * XDBL_W / 4 + 255) / 256, blk, 0, stream>>>(
        part, xdbl, M_TOTAL * XDBL_W);

    // 4) sp_T = softplus(W_dt @ dt_raw^T + bias)  [1280][4096]
    //    (overwrites the pre-split W_in/hs buffers -- they are dead now)
    gemm_tn<0, 2><<<dim3(M_TOTAL / BN, D_INNER / BM), blk, 0, stream>>>(
        W_dt, xdbl, spT, D_INNER, M_TOTAL, DT_RANK, DT_RANK, XDBL_W, M_TOTAL,
        dt_bias);

    // 5a) chunk-local (h_end, P) for chunks 0..2   (2560*3 one-wave blocks)
    scan_part1<<<BATCH * D_INNER * (NCHUNK - 1), 64, 0, stream>>>(
        xdbl, spT, A_log, uT, rec);

    // 5b) per-chunk y scan with combined h_start   (2560*4 one-wave blocks)
    scan_part3<<<BATCH * D_INNER * NCHUNK, 64, 0, stream>>>(
        gT, xdbl, spT, A_log, D_skip, rec, uT);

    // 5c) split W_out (gT region, g is dead after scan)
    split_kernel<<<(nWO / 4 + 255) / 256, blk, 0, stream>>>(W_out, WOhi, WOlo, nWO);

    // 5d) transpose+split y: uT [1280][4096] -> yNhi/yNlo [4096][1280] bf16
    transpose_split_kernel<<<dim3(M_TOTAL / 32, D_INNER / 32), blk, 0, stream>>>(
        uT, yNhi, yNlo);

    // 6) out = y @ W_out^T                [4096][640]   (pre-split MFMA)
    gemm_mfma_bf16<0><<<dim3(D_MODEL / 128, M_TOTAL / 128), blk, 0, stream>>>(
        yNhi, yNlo, WOhi, WOlo, out, M_TOTAL, D_MODEL, D_INNER,
        D_INNER, D_INNER, D_MODEL);
}